// Round 7
// baseline (258.415 us; speedup 1.0000x reference)
//
#include <hip/hip_runtime.h>
#include <stdint.h>

// SMHA: sigmoid multi-head attention, L=2048 B=2 E=1024 H=16 hd=64.
// Pipeline: convert(f32->bf16) -> inproj GEMM -> fused {attention + avg}
//           -> outproj GEMM.
// R7 (= R6 + one change): avg branch LDS cut 64KB -> 48KB (K stays
// double-buffered, Q single-buffered with a 2nd barrier after compute).
// Union smem 51.2KB -> 3 blocks/CU (was 2) so the merged kernel gets 50%
// more co-resident barrier groups (the mechanism that won in R6).
//  - attn branch / gemm_core / k_inproj / k_outproj / k_convert: unchanged.

#define L_SEQ 2048
#define NBATCH 2
#define EMB 1024
#define NHEAD 16
#define HD 64
#define MROWS 4096  // B*L

typedef __bf16 bf16x8 __attribute__((ext_vector_type(8)));
typedef float f32x4 __attribute__((ext_vector_type(4)));

#define WAITVM(N) asm volatile("s_waitcnt vmcnt(" #N ")" ::: "memory")
#define WAITLG() asm volatile("s_waitcnt lgkmcnt(0)" ::: "memory")
#define SBAR()                                  \
  do {                                          \
    asm volatile("" ::: "memory");              \
    __builtin_amdgcn_s_barrier();               \
    asm volatile("" ::: "memory");              \
  } while (0)

#if __has_builtin(__builtin_amdgcn_exp2f)
#define EXP2F(x) __builtin_amdgcn_exp2f(x)
#else
#define EXP2F(x) exp2f(x)
#endif

__device__ __forceinline__ unsigned short f2bf(float f) {
  union { float f; uint32_t u; } v; v.f = f;
  uint32_t u = v.u;
  u += 0x7fffu + ((u >> 16) & 1u);  // RNE
  return (unsigned short)(u >> 16);
}

__device__ __forceinline__ unsigned short f2bf_fast(float f) {
  union { float f; uint32_t u; } v; v.f = f;
  return (unsigned short)((v.u + 0x8000u) >> 16);
}

__device__ __forceinline__ void gl_lds16(const void* gptr, void* ldsptr) {
  const uint32_t* g = reinterpret_cast<const uint32_t*>(gptr);
  auto* l = reinterpret_cast<__attribute__((address_space(3))) uint32_t*>(
      reinterpret_cast<uintptr_t>(ldsptr));
  __builtin_amdgcn_global_load_lds(g, l, 16, 0, 0);
}

__device__ __forceinline__ f32x4 mfma16(bf16x8 a, bf16x8 b, f32x4 c) {
  return __builtin_amdgcn_mfma_f32_16x16x32_bf16(a, b, c, 0, 0, 0);
}

// st = -log2(e) * score (scale folded into Q at inproj): sigmoid(score)
__device__ __forceinline__ float fast_sigmoid2(float st) {
  float e = EXP2F(st);
  return __builtin_amdgcn_rcpf(1.0f + e);
}

// ---------------------------------------------------------------- K0: convert
__global__ __launch_bounds__(256) void k_convert(
    const float* __restrict__ qin, const float* __restrict__ kin,
    const float* __restrict__ vin, const float* __restrict__ win,
    const float* __restrict__ wo,
    unsigned short* __restrict__ Xq, unsigned short* __restrict__ Xk,
    unsigned short* __restrict__ Xv, unsigned short* __restrict__ Wb,
    unsigned short* __restrict__ Wob) {
  const int row = blockIdx.x;
  const int t = threadIdx.x;
  const float* src;
  unsigned short* dst;
  int srow;
  size_t drow;
  if (row < 3 * MROWS) {
    const int which = row >> 12;
    const int m = row & (MROWS - 1);
    const int b = m >> 11, l = m & (L_SEQ - 1);
    srow = l * NBATCH + b;  // input rows are (l, b)
    drow = (size_t)m;
    src = which == 0 ? qin : (which == 1 ? kin : vin);
    dst = which == 0 ? Xq : (which == 1 ? Xk : Xv);
  } else if (row < 3 * MROWS + 3072) {
    srow = row - 3 * MROWS; drow = (size_t)srow; src = win; dst = Wb;
  } else {
    srow = row - (3 * MROWS + 3072); drow = (size_t)srow; src = wo; dst = Wob;
  }
  const float4 vv = *(const float4*)(src + (size_t)srow * EMB + t * 4);
  ushort4 o;
  o.x = f2bf(vv.x); o.y = f2bf(vv.y); o.z = f2bf(vv.z); o.w = f2bf(vv.w);
  *(ushort4*)(dst + drow * EMB + t * 4) = o;
}

// --------------------------------------------------- shared GEMM core (BT)
// 3-stage pipelined: stage s lives in buf s%3. Per K-step: retire oldest
// stage (vmcnt(4): 8 outstanding -> 4), barrier, issue stage s+2, compute
// stage s. Prefetch distance = 2 compute regions; 8 loads in flight/wave.
__device__ __forceinline__ void gemm_issue(
    const unsigned short* __restrict__ A, const unsigned short* __restrict__ Bm,
    int m0, int n0, int k0, unsigned short* sA, unsigned short* sB) {
  const int tid = threadIdx.x;
  const int wave = tid >> 6;
  const int lane = tid & 63;
  const int srow = lane >> 2;
  const int scol = lane & 3;
  for (int i = 0; i < 2; ++i) {
    const int p = wave * 2 + i;
    const int r = p * 16 + srow;
    const int c = scol ^ ((r >> 1) & 3);
    gl_lds16(A + (size_t)(m0 + r) * EMB + k0 + c * 8, sA + p * 512);
    gl_lds16(Bm + (size_t)(n0 + r) * EMB + k0 + c * 8, sB + p * 512);
  }
}

__device__ __forceinline__ void gemm_core(
    const unsigned short* __restrict__ A, const unsigned short* __restrict__ Bm,
    int m0, int n0, unsigned short* sA, unsigned short* sB, f32x4 acc[4][4]) {
  const int tid = threadIdx.x;
  const int wave = tid >> 6;
  const int lane = tid & 63;
  const int quad = lane >> 4;
  const int l16 = lane & 15;
  const int wm = (wave >> 1) * 64;
  const int wn = (wave & 1) * 64;
  const int NSTEP = EMB / 32;

  for (int mi = 0; mi < 4; ++mi)
    for (int ni = 0; ni < 4; ++ni)
      acc[mi][ni] = (f32x4){0.f, 0.f, 0.f, 0.f};

  // prologue: stages 0,1 -> buf 0,1
  gemm_issue(A, Bm, m0, n0, 0, sA, sB);
  gemm_issue(A, Bm, m0, n0, 32, sA + 4096, sB + 4096);

  int cur = 0;
  for (int step = 0; step < NSTEP; ++step) {
    if (step < NSTEP - 1) { WAITVM(4); } else { WAITVM(0); }
    SBAR();  // oldest stage landed everywhere; buf[nxt] reads (step-1) sealed
    if (step + 2 < NSTEP) {
      int nxt = cur + 2; if (nxt >= 3) nxt -= 3;
      gemm_issue(A, Bm, m0, n0, (step + 2) * 32, sA + nxt * 4096,
                 sB + nxt * 4096);
    }
    const unsigned short* cA = sA + cur * 4096;
    const unsigned short* cB = sB + cur * 4096;
    bf16x8 af[4], bfr[4];
    for (int mi = 0; mi < 4; ++mi) {
      const int r = wm + mi * 16 + l16;
      const int cp = quad ^ ((r >> 1) & 3);
      af[mi] = *(const bf16x8*)(cA + r * 32 + cp * 8);
    }
    for (int ni = 0; ni < 4; ++ni) {
      const int r = wn + ni * 16 + l16;
      const int cp = quad ^ ((r >> 1) & 3);
      bfr[ni] = *(const bf16x8*)(cB + r * 32 + cp * 8);
    }
    for (int mi = 0; mi < 4; ++mi)
      for (int ni = 0; ni < 4; ++ni)
        acc[mi][ni] = mfma16(af[mi], bfr[ni], acc[mi][ni]);
    cur = cur == 2 ? 0 : cur + 1;
  }
}

// ---------------------------------------------------------------- K1: inproj
// 1D grid 768, XCD-chunked decode: blocks sharing an A m-panel (all 8 n0)
// land on the same XCD -> A panels + whole B slab stay L2-resident.
__global__ __launch_bounds__(256) void k_inproj(
    const unsigned short* __restrict__ Xq, const unsigned short* __restrict__ Xk,
    const unsigned short* __restrict__ Xv, const unsigned short* __restrict__ Wb,
    const float* __restrict__ bias,
    unsigned short* __restrict__ qb, unsigned short* __restrict__ kb,
    unsigned short* __restrict__ vb) {
  __shared__ __attribute__((aligned(16))) unsigned short sA[3 * 128 * 32];
  __shared__ __attribute__((aligned(16))) unsigned short sB[3 * 128 * 32];
  const int bid = blockIdx.x;
  const int tile = (bid & 7) * 96 + (bid >> 3);  // 768 % 8 == 0: bijective
  const int z = tile >> 8;                        // 256 tiles per z
  const int rem = tile & 255;
  const int m0 = (rem >> 3) * 128;
  const int n0 = (rem & 7) * 128;
  const unsigned short* A = z == 0 ? Xq : (z == 1 ? Xk : Xv);
  f32x4 acc[4][4];
  gemm_core(A, Wb + (size_t)z * EMB * EMB, m0, n0, sA, sB, acc);

  const int tid = threadIdx.x, wave = tid >> 6, lane = tid & 63;
  const int quad = lane >> 4, l16 = lane & 15;
  const int wm = (wave >> 1) * 64, wn = (wave & 1) * 64;
  // Q gets -log2(e)/8 so attn sigmoid is rcp(1+exp2(st)) with no per-score mul
  const float scale = (z == 0) ? -0.18033688011112042f : 1.0f;
  unsigned short* dst01 = (z == 0) ? qb : kb;
  for (int ni = 0; ni < 4; ++ni) {
    const int n = n0 + wn + ni * 16 + l16;
    const float bv = bias[z * EMB + n];
    const int h = n >> 6, d = n & 63;
    for (int mi = 0; mi < 4; ++mi) {
      for (int r = 0; r < 4; ++r) {
        const int m = m0 + wm + mi * 16 + quad * 4 + r;
        const int b = m >> 11, l = m & (L_SEQ - 1);
        const unsigned short o = f2bf((acc[mi][ni][r] + bv) * scale);
        if (z == 2)
          vb[((size_t)(b * NHEAD + h) * HD + d) * L_SEQ + l] = o;
        else
          dst01[((size_t)(b * NHEAD + h) * L_SEQ + l) * HD + d] = o;
      }
    }
  }
}

// ----------------------------------------------------- K2: attention + avg
// Merged dispatch: 1024 blocks x 512 threads, 51.2KB smem union -> 3 blk/CU.
//   blocks [0,512):   attention body (R6 verbatim)
//   blocks [512,1024): avg body (K double-buffered, Q single-buffered,
//                      2 barriers per head)
__global__ __launch_bounds__(512) void k_attn_avg(
    const unsigned short* __restrict__ qb, const unsigned short* __restrict__ kb,
    const unsigned short* __restrict__ vb, unsigned short* __restrict__ oh,
    float* __restrict__ avg) {
  __shared__ __attribute__((aligned(16))) unsigned short smem[25600];  // 51.2KB

  const int aid = blockIdx.x;
  const int tid = threadIdx.x, wave = tid >> 6, lane = tid & 63;
  const int quad = lane >> 4, l16 = lane & 15;
  const int sr8 = lane >> 3, sc8 = lane & 7;

  if (aid < 512) {
    // ---------------- attention body ----------------
    unsigned short (*sK)[64 * 64] = (unsigned short (*)[64 * 64])(smem);
    unsigned short (*sV)[64 * 64] = (unsigned short (*)[64 * 64])(smem + 8192);
    unsigned short* sP = smem + 16384;  // 128 x 72

    const int bh = aid & 31;
    const int b = bh >> 4, h = bh & 15;
    const int l0 = (aid >> 5) * 128;
    const unsigned short* qg = qb + ((size_t)bh * L_SEQ + l0) * HD;
    const unsigned short* kg = kb + (size_t)bh * L_SEQ * HD;
    const unsigned short* vg = vb + (size_t)bh * HD * L_SEQ;

    const int W = wave * 16;  // this wave's l-rows

    // Q fragment (B-operand of S^T = K*Q^T) straight to registers
    bf16x8 qf0, qf1;
    {
      const unsigned short* qrow = qg + (size_t)(W + l16) * HD + quad * 8;
      qf0 = *(const bf16x8*)(qrow);
      qf1 = *(const bf16x8*)(qrow + 32);
    }

    // prologue: issue K/V (step 0) into buffer 0
    if (wave < 4) {
      for (int i = 0; i < 2; ++i) {
        const int p = wave * 2 + i;
        const int r = p * 8 + sr8;
        const int c = sc8 ^ (r & 7);
        gl_lds16(kg + (size_t)r * HD + c * 8, sK[0] + p * 512);
      }
    } else {
      for (int i = 0; i < 2; ++i) {
        const int p = (wave - 4) * 2 + i;
        const int r = p * 8 + sr8;
        const int c = sc8 ^ (r & 7);
        gl_lds16(vg + (size_t)r * L_SEQ + c * 8, sV[0] + p * 512);
      }
    }

    f32x4 oacc[4];
    for (int ni = 0; ni < 4; ++ni) oacc[ni] = (f32x4){0.f, 0.f, 0.f, 0.f};
    f32x4 dacc = (f32x4){0.f, 0.f, 0.f, 0.f};

    bf16x8 ones;
    for (int j = 0; j < 8; ++j) ones[j] = (__bf16)1.0f;

    const int NS = L_SEQ / 64;  // 32 s-steps
    for (int it = 0; it < NS; ++it) {
      const int cur = it & 1;
      WAITVM(0);  // my staging for buf[cur] landed (issued a full region ago)
      SBAR();     // everyone's landed; prior reads of buf[cur^1] done
      if (it + 1 < NS) {
        const int s0n = (it + 1) * 64;
        if (wave < 4) {
          for (int i = 0; i < 2; ++i) {
            const int p = wave * 2 + i;
            const int r = p * 8 + sr8;
            const int c = sc8 ^ (r & 7);
            gl_lds16(kg + (size_t)(s0n + r) * HD + c * 8, sK[cur ^ 1] + p * 512);
          }
        } else {
          for (int i = 0; i < 2; ++i) {
            const int p = (wave - 4) * 2 + i;
            const int r = p * 8 + sr8;
            const int c = sc8 ^ (r & 7);
            gl_lds16(vg + (size_t)r * L_SEQ + s0n + c * 8, sV[cur ^ 1] + p * 512);
          }
        }
      }

      // QK: S^T for s in [0,64) x l in [W,W+16)
      f32x4 st[4];
      for (int smi = 0; smi < 4; ++smi) st[smi] = (f32x4){0.f, 0.f, 0.f, 0.f};
      {  // kk = 0
        for (int smi = 0; smi < 4; ++smi) {
          const int r = smi * 16 + l16;
          const int c = quad ^ (r & 7);
          bf16x8 a = *(const bf16x8*)(sK[cur] + r * 64 + c * 8);
          st[smi] = mfma16(a, qf0, st[smi]);
        }
      }
      {  // kk = 32
        for (int smi = 0; smi < 4; ++smi) {
          const int r = smi * 16 + l16;
          const int c = (4 + quad) ^ (r & 7);
          bf16x8 a = *(const bf16x8*)(sK[cur] + r * 64 + c * 8);
          st[smi] = mfma16(a, qf1, st[smi]);
        }
      }

      // sigmoid + perm-pack -> this wave's own sP rows [W, W+16)
      for (int smi = 0; smi < 4; ++smi) {
        uint32_t u[4];
        for (int r = 0; r < 4; ++r) {
          union { float f; uint32_t i; } cv;
          cv.f = fast_sigmoid2(st[smi][r]);
          u[r] = cv.i + 0x8000u;  // round-half-up bf16
        }
        uint2 pk;
        pk.x = __builtin_amdgcn_perm(u[1], u[0], 0x07060302u);
        pk.y = __builtin_amdgcn_perm(u[3], u[2], 0x07060302u);
        *(uint2*)(sP + (size_t)(W + l16) * 72 + smi * 16 + quad * 4) = pk;
      }
      WAITLG();  // own sP writes retired (wave-private rows; no barrier)

      // out += P*V ; den += P*1
      const int lr = W + l16;
      for (int kk = 0; kk < 64; kk += 32) {
        bf16x8 ap = *(const bf16x8*)(sP + (size_t)lr * 72 + kk + quad * 8);
        for (int ni = 0; ni < 4; ++ni) {
          const int rd = ni * 16 + l16;
          const int c = ((kk >> 3) + quad) ^ (rd & 7);
          bf16x8 bv4 = *(const bf16x8*)(sV[cur] + rd * 64 + c * 8);
          oacc[ni] = mfma16(ap, bv4, oacc[ni]);
        }
        dacc = mfma16(ap, ones, dacc);
      }
    }

    // normalize + write (den rows == oacc rows in C-layout)
    for (int r = 0; r < 4; ++r) {
      const int lrow = l0 + wave * 16 + quad * 4 + r;
      const float rden = __builtin_amdgcn_rcpf(dacc[r] + 1e-4f);
      unsigned short* dst = oh + ((size_t)(b * L_SEQ + lrow)) * EMB + h * HD;
      for (int ni = 0; ni < 4; ++ni)
        dst[ni * 16 + l16] = f2bf_fast(oacc[ni][r] * rden);
    }
  } else {
    // ---------------- avg body (Q single-buffered, K double-buffered) -----
    unsigned short* sQs = smem;  // 128x64 (16KB), single buffer
    unsigned short (*sKd)[128 * 64] =
        (unsigned short (*)[128 * 64])(smem + 8192);  // 2 x 16KB

    const int avgid = aid - 512;
    const int ss0 = (avgid & 15) * 128;
    const int l0 = ((avgid >> 4) & 15) * 128;
    const int b = avgid >> 8;
    const int wm = (wave & 1) * 64, wn = (wave >> 1) * 32;

    f32x4 av[4][2];
    for (int mi = 0; mi < 4; ++mi)
      for (int ni = 0; ni < 2; ++ni) av[mi][ni] = (f32x4){0.f, 0.f, 0.f, 0.f};

    auto stage_q = [&](int hh) {
      const unsigned short* qg =
          qb + ((size_t)(b * NHEAD + hh) * L_SEQ + l0) * HD;
      for (int i = 0; i < 2; ++i) {
        const int p = wave * 2 + i;
        const int r = p * 8 + sr8;
        const int c = sc8 ^ (r & 7);
        gl_lds16(qg + (size_t)r * HD + c * 8, sQs + p * 512);
      }
    };
    auto stage_k = [&](int hh, int buf) {
      const unsigned short* kg =
          kb + ((size_t)(b * NHEAD + hh) * L_SEQ + ss0) * HD;
      for (int i = 0; i < 2; ++i) {
        const int p = wave * 2 + i;
        const int r = p * 8 + sr8;
        const int c = sc8 ^ (r & 7);
        gl_lds16(kg + (size_t)r * HD + c * 8, sKd[buf] + p * 512);
      }
    };

    // prologue: head 0
    stage_q(0);
    stage_k(0, 0);

    for (int h = 0; h < NHEAD; ++h) {
      const int cur = h & 1;
      WAITVM(0);  // Q(h) + K(h) staging landed (issued a full region ago)
      SBAR();     // everyone's staging landed
      if (h + 1 < NHEAD) stage_k(h + 1, cur ^ 1);  // K dbuf: issue early

      f32x4 scr[4][2];
      for (int mi = 0; mi < 4; ++mi)
        for (int ni = 0; ni < 2; ++ni) scr[mi][ni] = (f32x4){0.f, 0.f, 0.f, 0.f};
      for (int kk = 0; kk < HD; kk += 32) {
        bf16x8 a[4], bbv[2];
        for (int mi = 0; mi < 4; ++mi) {
          const int r = wm + mi * 16 + l16;
          const int c = ((kk >> 3) + quad) ^ (r & 7);
          a[mi] = *(const bf16x8*)(sQs + r * 64 + c * 8);
        }
        for (int ni = 0; ni < 2; ++ni) {
          const int r = wn + ni * 16 + l16;
          const int c = ((kk >> 3) + quad) ^ (r & 7);
          bbv[ni] = *(const bf16x8*)(sKd[cur] + r * 64 + c * 8);
        }
        for (int mi = 0; mi < 4; ++mi)
          for (int ni = 0; ni < 2; ++ni)
            scr[mi][ni] = mfma16(a[mi], bbv[ni], scr[mi][ni]);
      }
      for (int mi = 0; mi < 4; ++mi)
        for (int ni = 0; ni < 2; ++ni)
          for (int r = 0; r < 4; ++r)
            av[mi][ni][r] += fast_sigmoid2(scr[mi][ni][r]);

      SBAR();  // all reads of sQs (and sKd[cur]) done
      if (h + 1 < NHEAD) stage_q(h + 1);  // safe to overwrite Q now
    }

    for (int mi = 0; mi < 4; ++mi) {
      for (int r = 0; r < 4; ++r) {
        const int l = l0 + wm + mi * 16 + quad * 4 + r;
        float* dst = avg + ((size_t)b * L_SEQ + l) * L_SEQ + ss0 + wn;
        for (int ni = 0; ni < 2; ++ni)
          dst[ni * 16 + l16] = av[mi][ni][r] * 0.0625f;
      }
    }
  }
}

// ---------------------------------------------------------------- K4: outproj
// 1D grid 256, XCD-chunked decode (256 % 8 == 0: bijective).
__global__ __launch_bounds__(256) void k_outproj(
    const unsigned short* __restrict__ OH, const unsigned short* __restrict__ Wob,
    const float* __restrict__ ob, float* __restrict__ out) {
  __shared__ __attribute__((aligned(16))) unsigned short sA[3 * 128 * 32];
  __shared__ __attribute__((aligned(16))) unsigned short sB[3 * 128 * 32];
  const int bid = blockIdx.x;
  const int tile = (bid & 7) * 32 + (bid >> 3);
  const int m0 = (tile >> 3) * 128;
  const int n0 = (tile & 7) * 128;
  f32x4 acc[4][4];
  gemm_core(OH, Wob, m0, n0, sA, sB, acc);

  const int tid = threadIdx.x, wave = tid >> 6, lane = tid & 63;
  const int quad = lane >> 4, l16 = lane & 15;
  const int wm = (wave >> 1) * 64, wn = (wave & 1) * 64;
  for (int ni = 0; ni < 4; ++ni) {
    const int n = n0 + wn + ni * 16 + l16;
    const float bv = ob[n];
    for (int mi = 0; mi < 4; ++mi) {
      for (int r = 0; r < 4; ++r) {
        const int m = m0 + wm + mi * 16 + quad * 4 + r;
        const int b = m >> 11, l = m & (L_SEQ - 1);
        out[((size_t)l * NBATCH + b) * EMB + n] = acc[mi][ni][r] + bv;
      }
    }
  }
}

extern "C" void kernel_launch(void* const* d_in, const int* in_sizes, int n_in,
                              void* d_out, int out_size, void* d_ws, size_t ws_size,
                              hipStream_t stream) {
  (void)in_sizes; (void)n_in; (void)out_size;
  const float* qin = (const float*)d_in[0];
  const float* kin = (const float*)d_in[1];
  const float* vin = (const float*)d_in[2];
  const float* w   = (const float*)d_in[3];
  const float* bias = (const float*)d_in[4];
  const float* wo  = (const float*)d_in[5];
  const float* ob  = (const float*)d_in[6];
  float* out = (float*)d_out;

  unsigned short* Xq  = (unsigned short*)d_ws;
  unsigned short* Xk  = Xq + (size_t)MROWS * EMB;
  unsigned short* Xv  = Xk + (size_t)MROWS * EMB;
  unsigned short* Wb  = Xv + (size_t)MROWS * EMB;
  unsigned short* Wob = Wb + (size_t)3 * EMB * EMB;
  unsigned short* qbuf = Wob + (size_t)EMB * EMB;
  unsigned short* kbuf = qbuf + (size_t)MROWS * EMB;
  unsigned short* vbuf = kbuf + (size_t)MROWS * EMB;
  unsigned short* ohb  = vbuf + (size_t)MROWS * EMB;
  const size_t need = ((size_t)MROWS * EMB * 7 + (size_t)4 * EMB * EMB) * 2;
  if (ws_size < need) return;

  k_convert<<<16384, 256, 0, stream>>>(qin, kin, vin, w, wo, Xq, Xk, Xv, Wb, Wob);
  k_inproj<<<768, 256, 0, stream>>>(Xq, Xk, Xv, Wb, bias, qbuf, kbuf, vbuf);
  k_attn_avg<<<1024, 512, 0, stream>>>(qbuf, kbuf, vbuf, ohb,
                                       out + (size_t)MROWS * EMB);
  k_outproj<<<256, 256, 0, stream>>>(ohb, Wob, ob, out);
}

// Round 8
// 250.873 us; speedup vs baseline: 1.0301x; 1.0301x over previous
//
#include <hip/hip_runtime.h>
#include <stdint.h>

// SMHA: sigmoid multi-head attention, L=2048 B=2 E=1024 H=16 hd=64.
// Pipeline: convert(f32->bf16) -> inproj GEMM -> fused {attention + avg}
//           -> outproj GEMM.
// R8 (= R6 + one structural change in the attn branch):
//  - attn: each wave owns 32 l-rows (two 16-row groups) -> every K/V LDS
//    fragment read feeds TWO MFMAs (halves LDS bytes/FLOP, the measured
//    bottleneck) and barriers/staging amortize 2x. l-tile 256, 256 attn
//    blocks (1/CU). LDS 68KB union -> 2 blocks/CU; launch_bounds(512,4)
//    pins VGPR<=128 so occupancy stays LDS-capped, not VGPR-capped.
//  - avg: R6 double-buffered form verbatim (R7's single-buffered Q was a
//    small regression -> reverted).
//  - gemm_core/k_inproj/k_outproj/k_convert: unchanged.

#define L_SEQ 2048
#define NBATCH 2
#define EMB 1024
#define NHEAD 16
#define HD 64
#define MROWS 4096  // B*L

typedef __bf16 bf16x8 __attribute__((ext_vector_type(8)));
typedef float f32x4 __attribute__((ext_vector_type(4)));

#define WAITVM(N) asm volatile("s_waitcnt vmcnt(" #N ")" ::: "memory")
#define WAITLG() asm volatile("s_waitcnt lgkmcnt(0)" ::: "memory")
#define SBAR()                                  \
  do {                                          \
    asm volatile("" ::: "memory");              \
    __builtin_amdgcn_s_barrier();               \
    asm volatile("" ::: "memory");              \
  } while (0)

#if __has_builtin(__builtin_amdgcn_exp2f)
#define EXP2F(x) __builtin_amdgcn_exp2f(x)
#else
#define EXP2F(x) exp2f(x)
#endif

__device__ __forceinline__ unsigned short f2bf(float f) {
  union { float f; uint32_t u; } v; v.f = f;
  uint32_t u = v.u;
  u += 0x7fffu + ((u >> 16) & 1u);  // RNE
  return (unsigned short)(u >> 16);
}

__device__ __forceinline__ unsigned short f2bf_fast(float f) {
  union { float f; uint32_t u; } v; v.f = f;
  return (unsigned short)((v.u + 0x8000u) >> 16);
}

__device__ __forceinline__ void gl_lds16(const void* gptr, void* ldsptr) {
  const uint32_t* g = reinterpret_cast<const uint32_t*>(gptr);
  auto* l = reinterpret_cast<__attribute__((address_space(3))) uint32_t*>(
      reinterpret_cast<uintptr_t>(ldsptr));
  __builtin_amdgcn_global_load_lds(g, l, 16, 0, 0);
}

__device__ __forceinline__ f32x4 mfma16(bf16x8 a, bf16x8 b, f32x4 c) {
  return __builtin_amdgcn_mfma_f32_16x16x32_bf16(a, b, c, 0, 0, 0);
}

// st = -log2(e) * score (scale folded into Q at inproj): sigmoid(score)
__device__ __forceinline__ float fast_sigmoid2(float st) {
  float e = EXP2F(st);
  return __builtin_amdgcn_rcpf(1.0f + e);
}

// ---------------------------------------------------------------- K0: convert
__global__ __launch_bounds__(256) void k_convert(
    const float* __restrict__ qin, const float* __restrict__ kin,
    const float* __restrict__ vin, const float* __restrict__ win,
    const float* __restrict__ wo,
    unsigned short* __restrict__ Xq, unsigned short* __restrict__ Xk,
    unsigned short* __restrict__ Xv, unsigned short* __restrict__ Wb,
    unsigned short* __restrict__ Wob) {
  const int row = blockIdx.x;
  const int t = threadIdx.x;
  const float* src;
  unsigned short* dst;
  int srow;
  size_t drow;
  if (row < 3 * MROWS) {
    const int which = row >> 12;
    const int m = row & (MROWS - 1);
    const int b = m >> 11, l = m & (L_SEQ - 1);
    srow = l * NBATCH + b;  // input rows are (l, b)
    drow = (size_t)m;
    src = which == 0 ? qin : (which == 1 ? kin : vin);
    dst = which == 0 ? Xq : (which == 1 ? Xk : Xv);
  } else if (row < 3 * MROWS + 3072) {
    srow = row - 3 * MROWS; drow = (size_t)srow; src = win; dst = Wb;
  } else {
    srow = row - (3 * MROWS + 3072); drow = (size_t)srow; src = wo; dst = Wob;
  }
  const float4 vv = *(const float4*)(src + (size_t)srow * EMB + t * 4);
  ushort4 o;
  o.x = f2bf(vv.x); o.y = f2bf(vv.y); o.z = f2bf(vv.z); o.w = f2bf(vv.w);
  *(ushort4*)(dst + drow * EMB + t * 4) = o;
}

// --------------------------------------------------- shared GEMM core (BT)
// 3-stage pipelined: stage s lives in buf s%3. Per K-step: retire oldest
// stage (vmcnt(4): 8 outstanding -> 4), barrier, issue stage s+2, compute
// stage s. Prefetch distance = 2 compute regions; 8 loads in flight/wave.
__device__ __forceinline__ void gemm_issue(
    const unsigned short* __restrict__ A, const unsigned short* __restrict__ Bm,
    int m0, int n0, int k0, unsigned short* sA, unsigned short* sB) {
  const int tid = threadIdx.x;
  const int wave = tid >> 6;
  const int lane = tid & 63;
  const int srow = lane >> 2;
  const int scol = lane & 3;
  for (int i = 0; i < 2; ++i) {
    const int p = wave * 2 + i;
    const int r = p * 16 + srow;
    const int c = scol ^ ((r >> 1) & 3);
    gl_lds16(A + (size_t)(m0 + r) * EMB + k0 + c * 8, sA + p * 512);
    gl_lds16(Bm + (size_t)(n0 + r) * EMB + k0 + c * 8, sB + p * 512);
  }
}

__device__ __forceinline__ void gemm_core(
    const unsigned short* __restrict__ A, const unsigned short* __restrict__ Bm,
    int m0, int n0, unsigned short* sA, unsigned short* sB, f32x4 acc[4][4]) {
  const int tid = threadIdx.x;
  const int wave = tid >> 6;
  const int lane = tid & 63;
  const int quad = lane >> 4;
  const int l16 = lane & 15;
  const int wm = (wave >> 1) * 64;
  const int wn = (wave & 1) * 64;
  const int NSTEP = EMB / 32;

  for (int mi = 0; mi < 4; ++mi)
    for (int ni = 0; ni < 4; ++ni)
      acc[mi][ni] = (f32x4){0.f, 0.f, 0.f, 0.f};

  // prologue: stages 0,1 -> buf 0,1
  gemm_issue(A, Bm, m0, n0, 0, sA, sB);
  gemm_issue(A, Bm, m0, n0, 32, sA + 4096, sB + 4096);

  int cur = 0;
  for (int step = 0; step < NSTEP; ++step) {
    if (step < NSTEP - 1) { WAITVM(4); } else { WAITVM(0); }
    SBAR();  // oldest stage landed everywhere; buf[nxt] reads (step-1) sealed
    if (step + 2 < NSTEP) {
      int nxt = cur + 2; if (nxt >= 3) nxt -= 3;
      gemm_issue(A, Bm, m0, n0, (step + 2) * 32, sA + nxt * 4096,
                 sB + nxt * 4096);
    }
    const unsigned short* cA = sA + cur * 4096;
    const unsigned short* cB = sB + cur * 4096;
    bf16x8 af[4], bfr[4];
    for (int mi = 0; mi < 4; ++mi) {
      const int r = wm + mi * 16 + l16;
      const int cp = quad ^ ((r >> 1) & 3);
      af[mi] = *(const bf16x8*)(cA + r * 32 + cp * 8);
    }
    for (int ni = 0; ni < 4; ++ni) {
      const int r = wn + ni * 16 + l16;
      const int cp = quad ^ ((r >> 1) & 3);
      bfr[ni] = *(const bf16x8*)(cB + r * 32 + cp * 8);
    }
    for (int mi = 0; mi < 4; ++mi)
      for (int ni = 0; ni < 4; ++ni)
        acc[mi][ni] = mfma16(af[mi], bfr[ni], acc[mi][ni]);
    cur = cur == 2 ? 0 : cur + 1;
  }
}

// ---------------------------------------------------------------- K1: inproj
// 1D grid 768, XCD-chunked decode: blocks sharing an A m-panel (all 8 n0)
// land on the same XCD -> A panels + whole B slab stay L2-resident.
__global__ __launch_bounds__(256) void k_inproj(
    const unsigned short* __restrict__ Xq, const unsigned short* __restrict__ Xk,
    const unsigned short* __restrict__ Xv, const unsigned short* __restrict__ Wb,
    const float* __restrict__ bias,
    unsigned short* __restrict__ qb, unsigned short* __restrict__ kb,
    unsigned short* __restrict__ vb) {
  __shared__ __attribute__((aligned(16))) unsigned short sA[3 * 128 * 32];
  __shared__ __attribute__((aligned(16))) unsigned short sB[3 * 128 * 32];
  const int bid = blockIdx.x;
  const int tile = (bid & 7) * 96 + (bid >> 3);  // 768 % 8 == 0: bijective
  const int z = tile >> 8;                        // 256 tiles per z
  const int rem = tile & 255;
  const int m0 = (rem >> 3) * 128;
  const int n0 = (rem & 7) * 128;
  const unsigned short* A = z == 0 ? Xq : (z == 1 ? Xk : Xv);
  f32x4 acc[4][4];
  gemm_core(A, Wb + (size_t)z * EMB * EMB, m0, n0, sA, sB, acc);

  const int tid = threadIdx.x, wave = tid >> 6, lane = tid & 63;
  const int quad = lane >> 4, l16 = lane & 15;
  const int wm = (wave >> 1) * 64, wn = (wave & 1) * 64;
  // Q gets -log2(e)/8 so attn sigmoid is rcp(1+exp2(st)) with no per-score mul
  const float scale = (z == 0) ? -0.18033688011112042f : 1.0f;
  unsigned short* dst01 = (z == 0) ? qb : kb;
  for (int ni = 0; ni < 4; ++ni) {
    const int n = n0 + wn + ni * 16 + l16;
    const float bv = bias[z * EMB + n];
    const int h = n >> 6, d = n & 63;
    for (int mi = 0; mi < 4; ++mi) {
      for (int r = 0; r < 4; ++r) {
        const int m = m0 + wm + mi * 16 + quad * 4 + r;
        const int b = m >> 11, l = m & (L_SEQ - 1);
        const unsigned short o = f2bf((acc[mi][ni][r] + bv) * scale);
        if (z == 2)
          vb[((size_t)(b * NHEAD + h) * HD + d) * L_SEQ + l] = o;
        else
          dst01[((size_t)(b * NHEAD + h) * L_SEQ + l) * HD + d] = o;
      }
    }
  }
}

// ----------------------------------------------------- K2: attention + avg
// Merged dispatch: 768 blocks x 512 threads, 68KB smem union -> 2 blk/CU.
//   blocks [0,256):   attention, l-tile 256, wave owns 32 l-rows
//   blocks [256,768): avg body (R6 double-buffered form)
__global__ __launch_bounds__(512, 4) void k_attn_avg(
    const unsigned short* __restrict__ qb, const unsigned short* __restrict__ kb,
    const unsigned short* __restrict__ vb, unsigned short* __restrict__ oh,
    float* __restrict__ avg) {
  __shared__ __attribute__((aligned(16))) unsigned short smem[34816];  // 68KB

  const int aid = blockIdx.x;
  const int tid = threadIdx.x, wave = tid >> 6, lane = tid & 63;
  const int quad = lane >> 4, l16 = lane & 15;
  const int sr8 = lane >> 3, sc8 = lane & 7;

  if (aid < 256) {
    // ---------------- attention body (32 l-rows per wave) ----------------
    unsigned short (*sK)[64 * 64] = (unsigned short (*)[64 * 64])(smem);
    unsigned short (*sV)[64 * 64] = (unsigned short (*)[64 * 64])(smem + 8192);
    unsigned short* sP = smem + 16384;  // 256 x 72

    const int bh = aid & 31;
    const int b = bh >> 4, h = bh & 15;
    const int l0 = (aid >> 5) * 256;
    const unsigned short* qg = qb + ((size_t)bh * L_SEQ + l0) * HD;
    const unsigned short* kg = kb + (size_t)bh * L_SEQ * HD;
    const unsigned short* vg = vb + (size_t)bh * HD * L_SEQ;

    const int W = wave * 32;  // this wave's l-rows [W, W+32)

    // Q fragments (B-operand of S^T = K*Q^T) in registers, 2 row-groups
    bf16x8 qf[2][2];
    for (int g = 0; g < 2; ++g) {
      const unsigned short* qrow =
          qg + (size_t)(W + g * 16 + l16) * HD + quad * 8;
      qf[g][0] = *(const bf16x8*)(qrow);
      qf[g][1] = *(const bf16x8*)(qrow + 32);
    }

    // prologue: issue K/V (step 0) into buffer 0
    if (wave < 4) {
      for (int i = 0; i < 2; ++i) {
        const int p = wave * 2 + i;
        const int r = p * 8 + sr8;
        const int c = sc8 ^ (r & 7);
        gl_lds16(kg + (size_t)r * HD + c * 8, sK[0] + p * 512);
      }
    } else {
      for (int i = 0; i < 2; ++i) {
        const int p = (wave - 4) * 2 + i;
        const int r = p * 8 + sr8;
        const int c = sc8 ^ (r & 7);
        gl_lds16(vg + (size_t)r * L_SEQ + c * 8, sV[0] + p * 512);
      }
    }

    f32x4 oacc[2][4];
    f32x4 dacc[2];
    for (int g = 0; g < 2; ++g) {
      for (int ni = 0; ni < 4; ++ni) oacc[g][ni] = (f32x4){0.f, 0.f, 0.f, 0.f};
      dacc[g] = (f32x4){0.f, 0.f, 0.f, 0.f};
    }

    bf16x8 ones;
    for (int j = 0; j < 8; ++j) ones[j] = (__bf16)1.0f;

    const int NS = L_SEQ / 64;  // 32 s-steps
    for (int it = 0; it < NS; ++it) {
      const int cur = it & 1;
      WAITVM(0);  // my staging for buf[cur] landed (issued a full region ago)
      SBAR();     // everyone's landed; prior reads of buf[cur^1] done
      if (it + 1 < NS) {
        const int s0n = (it + 1) * 64;
        if (wave < 4) {
          for (int i = 0; i < 2; ++i) {
            const int p = wave * 2 + i;
            const int r = p * 8 + sr8;
            const int c = sc8 ^ (r & 7);
            gl_lds16(kg + (size_t)(s0n + r) * HD + c * 8, sK[cur ^ 1] + p * 512);
          }
        } else {
          for (int i = 0; i < 2; ++i) {
            const int p = (wave - 4) * 2 + i;
            const int r = p * 8 + sr8;
            const int c = sc8 ^ (r & 7);
            gl_lds16(vg + (size_t)r * L_SEQ + s0n + c * 8, sV[cur ^ 1] + p * 512);
          }
        }
      }

      // QK: S^T for s in [0,64) x l-rows W..W+32 (each K read feeds 2 MFMAs)
      f32x4 st[2][4];
      for (int g = 0; g < 2; ++g)
        for (int smi = 0; smi < 4; ++smi) st[g][smi] = (f32x4){0.f, 0.f, 0.f, 0.f};
      {  // kk = 0
        for (int smi = 0; smi < 4; ++smi) {
          const int r = smi * 16 + l16;
          const int c = quad ^ (r & 7);
          bf16x8 a = *(const bf16x8*)(sK[cur] + r * 64 + c * 8);
          st[0][smi] = mfma16(a, qf[0][0], st[0][smi]);
          st[1][smi] = mfma16(a, qf[1][0], st[1][smi]);
        }
      }
      {  // kk = 32
        for (int smi = 0; smi < 4; ++smi) {
          const int r = smi * 16 + l16;
          const int c = (4 + quad) ^ (r & 7);
          bf16x8 a = *(const bf16x8*)(sK[cur] + r * 64 + c * 8);
          st[0][smi] = mfma16(a, qf[0][1], st[0][smi]);
          st[1][smi] = mfma16(a, qf[1][1], st[1][smi]);
        }
      }

      // sigmoid + perm-pack -> this wave's own sP rows
      for (int g = 0; g < 2; ++g) {
        for (int smi = 0; smi < 4; ++smi) {
          uint32_t u[4];
          for (int r = 0; r < 4; ++r) {
            union { float f; uint32_t i; } cv;
            cv.f = fast_sigmoid2(st[g][smi][r]);
            u[r] = cv.i + 0x8000u;  // round-half-up bf16
          }
          uint2 pk;
          pk.x = __builtin_amdgcn_perm(u[1], u[0], 0x07060302u);
          pk.y = __builtin_amdgcn_perm(u[3], u[2], 0x07060302u);
          *(uint2*)(sP + (size_t)(W + g * 16 + l16) * 72 + smi * 16 + quad * 4) =
              pk;
        }
      }
      WAITLG();  // own sP writes retired (wave-private rows; no barrier)

      // out += P*V ; den += P*1  (each V read feeds 2 MFMAs)
      {  // kk = 0
        bf16x8 ap0 = *(const bf16x8*)(sP + (size_t)(W + l16) * 72 + quad * 8);
        bf16x8 ap1 =
            *(const bf16x8*)(sP + (size_t)(W + 16 + l16) * 72 + quad * 8);
        for (int ni = 0; ni < 4; ++ni) {
          const int rd = ni * 16 + l16;
          const int c = quad ^ (rd & 7);
          bf16x8 bv4 = *(const bf16x8*)(sV[cur] + rd * 64 + c * 8);
          oacc[0][ni] = mfma16(ap0, bv4, oacc[0][ni]);
          oacc[1][ni] = mfma16(ap1, bv4, oacc[1][ni]);
        }
        dacc[0] = mfma16(ap0, ones, dacc[0]);
        dacc[1] = mfma16(ap1, ones, dacc[1]);
      }
      {  // kk = 32
        bf16x8 ap0 =
            *(const bf16x8*)(sP + (size_t)(W + l16) * 72 + 32 + quad * 8);
        bf16x8 ap1 =
            *(const bf16x8*)(sP + (size_t)(W + 16 + l16) * 72 + 32 + quad * 8);
        for (int ni = 0; ni < 4; ++ni) {
          const int rd = ni * 16 + l16;
          const int c = (4 + quad) ^ (rd & 7);
          bf16x8 bv4 = *(const bf16x8*)(sV[cur] + rd * 64 + c * 8);
          oacc[0][ni] = mfma16(ap0, bv4, oacc[0][ni]);
          oacc[1][ni] = mfma16(ap1, bv4, oacc[1][ni]);
        }
        dacc[0] = mfma16(ap0, ones, dacc[0]);
        dacc[1] = mfma16(ap1, ones, dacc[1]);
      }
    }

    // normalize + write (den rows == oacc rows in C-layout)
    for (int g = 0; g < 2; ++g) {
      for (int r = 0; r < 4; ++r) {
        const int lrow = l0 + W + g * 16 + quad * 4 + r;
        const float rden = __builtin_amdgcn_rcpf(dacc[g][r] + 1e-4f);
        unsigned short* dst = oh + ((size_t)(b * L_SEQ + lrow)) * EMB + h * HD;
        for (int ni = 0; ni < 4; ++ni)
          dst[ni * 16 + l16] = f2bf_fast(oacc[g][ni][r] * rden);
      }
    }
  } else {
    // ---------------- avg body (R6 double-buffered) ----------------
    unsigned short (*sQ)[128 * 64] = (unsigned short (*)[128 * 64])(smem);
    unsigned short (*sK)[128 * 64] = (unsigned short (*)[128 * 64])(smem + 16384);

    const int avgid = aid - 256;
    const int ss0 = (avgid & 15) * 128;
    const int l0 = ((avgid >> 4) & 15) * 128;
    const int b = avgid >> 8;
    const int wm = (wave & 1) * 64, wn = (wave >> 1) * 32;

    f32x4 av[4][2];
    for (int mi = 0; mi < 4; ++mi)
      for (int ni = 0; ni < 2; ++ni) av[mi][ni] = (f32x4){0.f, 0.f, 0.f, 0.f};

    auto stage = [&](int hh, int buf) {
      const unsigned short* qg =
          qb + ((size_t)(b * NHEAD + hh) * L_SEQ + l0) * HD;
      const unsigned short* kg =
          kb + ((size_t)(b * NHEAD + hh) * L_SEQ + ss0) * HD;
      for (int i = 0; i < 2; ++i) {
        const int p = wave * 2 + i;
        const int r = p * 8 + sr8;
        const int c = sc8 ^ (r & 7);
        gl_lds16(qg + (size_t)r * HD + c * 8, sQ[buf] + p * 512);
        gl_lds16(kg + (size_t)r * HD + c * 8, sK[buf] + p * 512);
      }
    };

    stage(0, 0);  // prologue

    for (int h = 0; h < NHEAD; ++h) {
      const int cur = h & 1;
      WAITVM(0);  // my head-h loads landed (issued a full region ago)
      SBAR();     // everyone's landed; prior head's reads of buf[cur^1] done
      if (h + 1 < NHEAD) stage(h + 1, cur ^ 1);

      f32x4 scr[4][2];
      for (int mi = 0; mi < 4; ++mi)
        for (int ni = 0; ni < 2; ++ni) scr[mi][ni] = (f32x4){0.f, 0.f, 0.f, 0.f};
      for (int kk = 0; kk < HD; kk += 32) {
        bf16x8 a[4], bbv[2];
        for (int mi = 0; mi < 4; ++mi) {
          const int r = wm + mi * 16 + l16;
          const int c = ((kk >> 3) + quad) ^ (r & 7);
          a[mi] = *(const bf16x8*)(sQ[cur] + r * 64 + c * 8);
        }
        for (int ni = 0; ni < 2; ++ni) {
          const int r = wn + ni * 16 + l16;
          const int c = ((kk >> 3) + quad) ^ (r & 7);
          bbv[ni] = *(const bf16x8*)(sK[cur] + r * 64 + c * 8);
        }
        for (int mi = 0; mi < 4; ++mi)
          for (int ni = 0; ni < 2; ++ni)
            scr[mi][ni] = mfma16(a[mi], bbv[ni], scr[mi][ni]);
      }
      for (int mi = 0; mi < 4; ++mi)
        for (int ni = 0; ni < 2; ++ni)
          for (int r = 0; r < 4; ++r)
            av[mi][ni][r] += fast_sigmoid2(scr[mi][ni][r]);
    }

    for (int mi = 0; mi < 4; ++mi) {
      for (int r = 0; r < 4; ++r) {
        const int l = l0 + wm + mi * 16 + quad * 4 + r;
        float* dst = avg + ((size_t)b * L_SEQ + l) * L_SEQ + ss0 + wn;
        for (int ni = 0; ni < 2; ++ni)
          dst[ni * 16 + l16] = av[mi][ni][r] * 0.0625f;
      }
    }
  }
}

// ---------------------------------------------------------------- K4: outproj
// 1D grid 256, XCD-chunked decode (256 % 8 == 0: bijective).
__global__ __launch_bounds__(256) void k_outproj(
    const unsigned short* __restrict__ OH, const unsigned short* __restrict__ Wob,
    const float* __restrict__ ob, float* __restrict__ out) {
  __shared__ __attribute__((aligned(16))) unsigned short sA[3 * 128 * 32];
  __shared__ __attribute__((aligned(16))) unsigned short sB[3 * 128 * 32];
  const int bid = blockIdx.x;
  const int tile = (bid & 7) * 32 + (bid >> 3);
  const int m0 = (tile >> 3) * 128;
  const int n0 = (tile & 7) * 128;
  f32x4 acc[4][4];
  gemm_core(OH, Wob, m0, n0, sA, sB, acc);

  const int tid = threadIdx.x, wave = tid >> 6, lane = tid & 63;
  const int quad = lane >> 4, l16 = lane & 15;
  const int wm = (wave >> 1) * 64, wn = (wave & 1) * 64;
  for (int ni = 0; ni < 4; ++ni) {
    const int n = n0 + wn + ni * 16 + l16;
    const float bv = ob[n];
    for (int mi = 0; mi < 4; ++mi) {
      for (int r = 0; r < 4; ++r) {
        const int m = m0 + wm + mi * 16 + quad * 4 + r;
        const int b = m >> 11, l = m & (L_SEQ - 1);
        out[((size_t)l * NBATCH + b) * EMB + n] = acc[mi][ni][r] + bv;
      }
    }
  }
}

extern "C" void kernel_launch(void* const* d_in, const int* in_sizes, int n_in,
                              void* d_out, int out_size, void* d_ws, size_t ws_size,
                              hipStream_t stream) {
  (void)in_sizes; (void)n_in; (void)out_size;
  const float* qin = (const float*)d_in[0];
  const float* kin = (const float*)d_in[1];
  const float* vin = (const float*)d_in[2];
  const float* w   = (const float*)d_in[3];
  const float* bias = (const float*)d_in[4];
  const float* wo  = (const float*)d_in[5];
  const float* ob  = (const float*)d_in[6];
  float* out = (float*)d_out;

  unsigned short* Xq  = (unsigned short*)d_ws;
  unsigned short* Xk  = Xq + (size_t)MROWS * EMB;
  unsigned short* Xv  = Xk + (size_t)MROWS * EMB;
  unsigned short* Wb  = Xv + (size_t)MROWS * EMB;
  unsigned short* Wob = Wb + (size_t)3 * EMB * EMB;
  unsigned short* qbuf = Wob + (size_t)EMB * EMB;
  unsigned short* kbuf = qbuf + (size_t)MROWS * EMB;
  unsigned short* vbuf = kbuf + (size_t)MROWS * EMB;
  unsigned short* ohb  = vbuf + (size_t)MROWS * EMB;
  const size_t need = ((size_t)MROWS * EMB * 7 + (size_t)4 * EMB * EMB) * 2;
  if (ws_size < need) return;

  k_convert<<<16384, 256, 0, stream>>>(qin, kin, vin, w, wo, Xq, Xk, Xv, Wb, Wob);
  k_inproj<<<768, 256, 0, stream>>>(Xq, Xk, Xv, Wb, bias, qbuf, kbuf, vbuf);
  k_attn_avg<<<768, 512, 0, stream>>>(qbuf, kbuf, vbuf, ohb,
                                      out + (size_t)MROWS * EMB);
  k_outproj<<<256, 256, 0, stream>>>(ohb, Wob, ob, out);
}